// Round 7
// baseline (516.392 us; speedup 1.0000x reference)
//
#include <hip/hip_runtime.h>
#include <hip/hip_bf16.h>

#define EMB 1024
#define HSZ 64
#define NHEAD 16
#define SEQ 2048
#define NBATCH 2
#define NROWS (NBATCH * SEQ) // 4096

using short8 = __attribute__((ext_vector_type(8))) short;
using f32x4  = __attribute__((ext_vector_type(4))) float;

__device__ __forceinline__ unsigned short f2b(float f) {
    __hip_bfloat16 b = __float2bfloat16(f);
    return *reinterpret_cast<unsigned short*>(&b);
}

// ---------------- LayerNorm: one block per row, bf16 out ----------------
__global__ __launch_bounds__(256) void ln_kernel(const float* __restrict__ x,
                                                 const float* __restrict__ g,
                                                 const float* __restrict__ b,
                                                 unsigned short* __restrict__ out) {
    int row = blockIdx.x;
    int t = threadIdx.x;
    const float* xr = x + (size_t)row * EMB;
    float v[4];
    float s = 0.f, s2 = 0.f;
#pragma unroll
    for (int i = 0; i < 4; ++i) {
        v[i] = xr[t + i * 256];
        s += v[i];
        s2 += v[i] * v[i];
    }
#pragma unroll
    for (int off = 1; off < 64; off <<= 1) {
        s += __shfl_xor(s, off);
        s2 += __shfl_xor(s2, off);
    }
    __shared__ float aux[8];
    int wave = t >> 6, lane = t & 63;
    if (lane == 0) { aux[wave] = s; aux[4 + wave] = s2; }
    __syncthreads();
    s = aux[0] + aux[1] + aux[2] + aux[3];
    s2 = aux[4] + aux[5] + aux[6] + aux[7];
    float mu = s * (1.f / EMB);
    float var = s2 * (1.f / EMB) - mu * mu;
    float r = rsqrtf(var + 1e-5f);
    unsigned short* orow = out + (size_t)row * EMB;
#pragma unroll
    for (int i = 0; i < 4; ++i) {
        int c = t + i * 256;
        orow[c] = f2b((v[i] - mu) * r * g[c] + b[c]);
    }
}

// ---------------- Transpose + fp32->bf16 convert ----------------
// in: K x N fp32 row-major (+ z*K*N), out: N x K bf16 row-major (+ z*N*K).
__global__ __launch_bounds__(256) void transpose_to_bf16(const float* __restrict__ in,
                                                         unsigned short* __restrict__ out,
                                                         int K, int N) {
    in  += (size_t)blockIdx.z * K * N;
    out += (size_t)blockIdx.z * N * K;
    __shared__ float tile[32][33];
    int k0 = blockIdx.y * 32, n0 = blockIdx.x * 32;
    int t = threadIdx.x;
    int r = t >> 3, c4 = (t & 7) * 4;
    float4 v = *reinterpret_cast<const float4*>(&in[(size_t)(k0 + r) * N + n0 + c4]);
    tile[r][c4 + 0] = v.x; tile[r][c4 + 1] = v.y;
    tile[r][c4 + 2] = v.z; tile[r][c4 + 3] = v.w;
    __syncthreads();
    ushort4 o;
    o.x = f2b(tile[c4 + 0][r]);
    o.y = f2b(tile[c4 + 1][r]);
    o.z = f2b(tile[c4 + 2][r]);
    o.w = f2b(tile[c4 + 3][r]);
    *reinterpret_cast<ushort4*>(&out[(size_t)(n0 + r) * K + k0 + c4]) = o;
}

// ---------------- bf16 MFMA GEMM (m97 structure) ----------------
// C[M,N] = A[M,K] @ Bt[N,K]^T  (+bias)(+resid)(relu?), A/Bt bf16, acc fp32.
// BM=BN=128, BK=32, 256 threads = 4 waves (2x2), each wave 64x64 = 4x4 mfma_16x16x32 frags.
// SPLIT: N = 3x1024 (QKV fused); column block selects sub-buffer at C + (c>>10)*M*1024.
template <bool OUT_BF16, bool RELU, bool BIAS, bool RESID, bool SPLIT>
__global__ __launch_bounds__(256) void gemm_bf16(
    const unsigned short* __restrict__ A, const unsigned short* __restrict__ Bt,
    const float* __restrict__ bias, const float* __restrict__ resid,
    void* __restrict__ Cv, int M, int N, int K) {
    __shared__ unsigned short As[128 * 32];
    __shared__ unsigned short Bs[128 * 32];
    int c0 = blockIdx.x * 128, r0 = blockIdx.y * 128;
    int tid = threadIdx.x;
    int w = tid >> 6, l = tid & 63;
    int wr = w >> 1, wc = w & 1;

    f32x4 zero = {0.f, 0.f, 0.f, 0.f};
    f32x4 acc[4][4];
#pragma unroll
    for (int i = 0; i < 4; ++i)
#pragma unroll
        for (int j = 0; j < 4; ++j) acc[i][j] = zero;

    const unsigned short* Ab = A + (size_t)r0 * K;
    const unsigned short* Bb = Bt + (size_t)c0 * K;
    int srow = w * 32 + (l >> 2);   // staging row within tile (plus i*16)
    int scol = (l & 3) * 8;         // staging element col (16B granule)

    for (int k0 = 0; k0 < K; k0 += 32) {
#pragma unroll
        for (int i = 0; i < 2; ++i) {
            __builtin_amdgcn_global_load_lds(
                (const __attribute__((address_space(1))) void*)(Ab + (size_t)(srow + i * 16) * K + k0 + scol),
                (__attribute__((address_space(3))) void*)(&As[(w * 32 + i * 16) * 32]),
                16, 0, 0);
            __builtin_amdgcn_global_load_lds(
                (const __attribute__((address_space(1))) void*)(Bb + (size_t)(srow + i * 16) * K + k0 + scol),
                (__attribute__((address_space(3))) void*)(&Bs[(w * 32 + i * 16) * 32]),
                16, 0, 0);
        }
        __syncthreads();
        short8 a[4], b[4];
#pragma unroll
        for (int mi = 0; mi < 4; ++mi)
            a[mi] = *reinterpret_cast<const short8*>(&As[(wr * 64 + mi * 16 + (l & 15)) * 32 + (l >> 4) * 8]);
#pragma unroll
        for (int ni = 0; ni < 4; ++ni)
            b[ni] = *reinterpret_cast<const short8*>(&Bs[(wc * 64 + ni * 16 + (l & 15)) * 32 + (l >> 4) * 8]);
#pragma unroll
        for (int mi = 0; mi < 4; ++mi)
#pragma unroll
            for (int ni = 0; ni < 4; ++ni)
                acc[mi][ni] = __builtin_amdgcn_mfma_f32_16x16x32_bf16(a[mi], b[ni], acc[mi][ni], 0, 0, 0);
        __syncthreads();
    }

    // Epilogue. C/D layout: col = lane&15, row = (lane>>4)*4 + reg  [m89 verified]
#pragma unroll
    for (int mi = 0; mi < 4; ++mi) {
#pragma unroll
        for (int r = 0; r < 4; ++r) {
            int row = r0 + wr * 64 + mi * 16 + (l >> 4) * 4 + r;
#pragma unroll
            for (int ni = 0; ni < 4; ++ni) {
                int colg = c0 + wc * 64 + ni * 16 + (l & 15);
                float v = acc[mi][ni][r];
                if (BIAS) v += bias[colg];
                if (RESID) v += resid[(size_t)row * N + colg];
                if (RELU) v = fmaxf(v, 0.f);
                size_t coff;
                if (SPLIT)
                    coff = (size_t)(colg >> 10) * (size_t)M * 1024 + (size_t)row * 1024 + (colg & 1023);
                else
                    coff = (size_t)row * N + colg;
                if (OUT_BF16) ((unsigned short*)Cv)[coff] = f2b(v);
                else          ((float*)Cv)[coff] = v;
            }
        }
    }
}

// ---------------- MFMA flash attention (bf16 in/out, causal) ----------------
// q,k,v,o bf16 [B*T, H*HS]; (b,t,h,d) at (b*SEQ+t)*EMB + h*64 + d. Scale = 1/32.
// Block: 256 thr = 4 waves; Q-tile 64 rows; wave w owns rows w*16..w*16+15 (full 64 cols).
// LDS rows padded to 72 shorts (144B = 9*16B): b128-aligned, ~2-way banks (free, m136).
__global__ __launch_bounds__(256) void attn_mfma(const unsigned short* __restrict__ q,
                                                 const unsigned short* __restrict__ k,
                                                 const unsigned short* __restrict__ v,
                                                 unsigned short* __restrict__ o) {
    int qt = blockIdx.x;
    int bh = blockIdx.y;
    int b = bh >> 4, h = bh & 15;
    const size_t base = (size_t)b * SEQ * EMB + (size_t)h * HSZ;
    __shared__ __align__(16) unsigned short Qs[64 * 72];
    __shared__ __align__(16) unsigned short Ks[64 * 72];
    __shared__ __align__(16) unsigned short Vt[64 * 72]; // transposed: [dim][kv]
    __shared__ __align__(16) unsigned short Ps[64 * 72];
    int tid = threadIdx.x, w = tid >> 6, l = tid & 63;
    int g = l >> 4, c = l & 15;

    // stage Q tile [64][64]
    for (int i = tid; i < 512; i += 256) {
        int r = i >> 3, s = i & 7;
        short8 t = *reinterpret_cast<const short8*>(&q[base + (size_t)(qt * 64 + r) * EMB + s * 8]);
        *reinterpret_cast<short8*>(&Qs[r * 72 + s * 8]) = t;
    }
    __syncthreads();
    short8 aq[2]; // Q A-frags, hoisted (rows w*16+c, dims kk*32 + g*8 ..+7)
    aq[0] = *reinterpret_cast<const short8*>(&Qs[(w * 16 + c) * 72 + g * 8]);
    aq[1] = *reinterpret_cast<const short8*>(&Qs[(w * 16 + c) * 72 + 32 + g * 8]);

    float m[4], lsum[4];
    f32x4 oacc[4];
    f32x4 zero = {0.f, 0.f, 0.f, 0.f};
#pragma unroll
    for (int r = 0; r < 4; ++r) { m[r] = -1e30f; lsum[r] = 0.f; }
#pragma unroll
    for (int ni = 0; ni < 4; ++ni) oacc[ni] = zero;

    for (int kt = 0; kt <= qt; ++kt) {
        __syncthreads(); // prior-tile PV reads of Ks/Vt done
        for (int i = tid; i < 512; i += 256) {
            int r = i >> 3, s = i & 7;
            short8 tk = *reinterpret_cast<const short8*>(&k[base + (size_t)(kt * 64 + r) * EMB + s * 8]);
            *reinterpret_cast<short8*>(&Ks[r * 72 + s * 8]) = tk;
            short8 tv = *reinterpret_cast<const short8*>(&v[base + (size_t)(kt * 64 + r) * EMB + s * 8]);
#pragma unroll
            for (int j = 0; j < 8; ++j)
                Vt[(s * 8 + j) * 72 + r] = ((unsigned short*)&tv)[j];
        }
        __syncthreads();
        // QK^T: S[16 x 64] per wave
        f32x4 sacc[4];
#pragma unroll
        for (int ni = 0; ni < 4; ++ni) sacc[ni] = zero;
        __builtin_amdgcn_s_setprio(1);
#pragma unroll
        for (int ni = 0; ni < 4; ++ni) {
            short8 bk0 = *reinterpret_cast<const short8*>(&Ks[(ni * 16 + c) * 72 + g * 8]);
            sacc[ni] = __builtin_amdgcn_mfma_f32_16x16x32_bf16(aq[0], bk0, sacc[ni], 0, 0, 0);
            short8 bk1 = *reinterpret_cast<const short8*>(&Ks[(ni * 16 + c) * 72 + 32 + g * 8]);
            sacc[ni] = __builtin_amdgcn_mfma_f32_16x16x32_bf16(aq[1], bk1, sacc[ni], 0, 0, 0);
        }
        __builtin_amdgcn_s_setprio(0);
        // online softmax; C layout: lane holds rows g*4+r, col ni*16+c
#pragma unroll
        for (int r = 0; r < 4; ++r) {
            int grow = w * 16 + g * 4 + r; // row within 64-row Q tile
            float sv[4];
            float rmax = -1e30f;
#pragma unroll
            for (int ni = 0; ni < 4; ++ni) {
                float s0 = sacc[ni][r] * 0.03125f;
                if (kt == qt && (ni * 16 + c) > grow) s0 = -1e30f;
                sv[ni] = s0;
                rmax = fmaxf(rmax, s0);
            }
#pragma unroll
            for (int off = 1; off < 16; off <<= 1) rmax = fmaxf(rmax, __shfl_xor(rmax, off));
            float mnew = fmaxf(m[r], rmax);
            float sc = __expf(m[r] - mnew);
            float ps = 0.f;
#pragma unroll
            for (int ni = 0; ni < 4; ++ni) {
                float p = __expf(sv[ni] - mnew);
                ps += p;
                Ps[grow * 72 + ni * 16 + c] = f2b(p);
            }
#pragma unroll
            for (int off = 1; off < 16; off <<= 1) ps += __shfl_xor(ps, off);
            lsum[r] = lsum[r] * sc + ps;
            m[r] = mnew;
#pragma unroll
            for (int ni = 0; ni < 4; ++ni) oacc[ni][r] *= sc;
        }
        __syncthreads(); // Ps visible
        // PV: O[16 x 64] += P[16 x 64] @ V[64 x 64]
        __builtin_amdgcn_s_setprio(1);
#pragma unroll
        for (int kk = 0; kk < 2; ++kk) {
            short8 ap = *reinterpret_cast<const short8*>(&Ps[(w * 16 + c) * 72 + kk * 32 + g * 8]);
#pragma unroll
            for (int ni = 0; ni < 4; ++ni) {
                short8 bv = *reinterpret_cast<const short8*>(&Vt[(ni * 16 + c) * 72 + kk * 32 + g * 8]);
                oacc[ni] = __builtin_amdgcn_mfma_f32_16x16x32_bf16(ap, bv, oacc[ni], 0, 0, 0);
            }
        }
        __builtin_amdgcn_s_setprio(0);
    }
#pragma unroll
    for (int r = 0; r < 4; ++r) {
        float inv = 1.f / lsum[r];
        size_t ro = base + (size_t)(qt * 64 + w * 16 + g * 4 + r) * EMB;
#pragma unroll
        for (int ni = 0; ni < 4; ++ni)
            o[ro + ni * 16 + c] = f2b(oacc[ni][r] * inv);
    }
}

extern "C" void kernel_launch(void* const* d_in, const int* in_sizes, int n_in,
                              void* d_out, int out_size, void* d_ws, size_t ws_size,
                              hipStream_t stream) {
    const float* x      = (const float*)d_in[0];
    const float* wq     = (const float*)d_in[1];
    const float* wk     = (const float*)d_in[2];
    const float* wv     = (const float*)d_in[3];
    const float* w_proj = (const float*)d_in[4];
    const float* b_proj = (const float*)d_in[5];
    const float* w1     = (const float*)d_in[6];
    const float* b1     = (const float*)d_in[7];
    const float* w2     = (const float*)d_in[8];
    const float* b2     = (const float*)d_in[9];
    const float* g1     = (const float*)d_in[10];
    const float* be1    = (const float*)d_in[11];
    const float* g2     = (const float*)d_in[12];
    const float* be2    = (const float*)d_in[13];
    float* out = (float*)d_out;

    const size_t MB = 1u << 20;
    char* w8 = (char*)d_ws;
    // Workspace plan (80 MB), phase-aliased:
    //  [0,16)   x1 fp32 (proj out; read by LN2 + FF2 resid)
    //  [16,24)  h_b bf16 (LN1 out; dead after QKV) -> h2b (LN2 out)
    //  [24,32)  qb bf16 \
    //  [32,40)  kb bf16  > dead after attention -> ffhb [24,56) 32MB
    //  [40,48)  vb bf16 /
    //  [48,56)  attnb bf16 (dead after proj)
    //  [56,64)  wqT,wkT,wvT,wpT (2MB each; qkv contiguous)
    //  [64,72)  w1T   [72,80) w2T
    float*          x1    = (float*)(w8 + 0);
    unsigned short* h_b   = (unsigned short*)(w8 + 16 * MB);
    unsigned short* h2b   = (unsigned short*)(w8 + 16 * MB);
    unsigned short* qb    = (unsigned short*)(w8 + 24 * MB);
    unsigned short* attnb = (unsigned short*)(w8 + 48 * MB);
    unsigned short* ffhb  = (unsigned short*)(w8 + 24 * MB);
    unsigned short* wqT   = (unsigned short*)(w8 + 56 * MB);
    unsigned short* wpT   = (unsigned short*)(w8 + 62 * MB);
    unsigned short* w1T   = (unsigned short*)(w8 + 64 * MB);
    unsigned short* w2T   = (unsigned short*)(w8 + 72 * MB);
    unsigned short* kb    = qb + (size_t)NROWS * EMB;
    unsigned short* vb    = kb + (size_t)NROWS * EMB;
    unsigned short* wkT   = wqT + (size_t)EMB * EMB;
    unsigned short* wvT   = wkT + (size_t)EMB * EMB;

    // Weight prep: transpose+convert to bf16 N x K ("B^T" form).
    transpose_to_bf16<<<dim3(2, 32, 16), 256, 0, stream>>>(wq, wqT, EMB, HSZ);
    transpose_to_bf16<<<dim3(2, 32, 16), 256, 0, stream>>>(wk, wkT, EMB, HSZ);
    transpose_to_bf16<<<dim3(2, 32, 16), 256, 0, stream>>>(wv, wvT, EMB, HSZ);
    transpose_to_bf16<<<dim3(32, 32, 1), 256, 0, stream>>>(w_proj, wpT, EMB, EMB);
    transpose_to_bf16<<<dim3(128, 32, 1), 256, 0, stream>>>(w1, w1T, EMB, 4 * EMB);
    transpose_to_bf16<<<dim3(32, 128, 1), 256, 0, stream>>>(w2, w2T, 4 * EMB, EMB);

    // LN1 -> bf16
    ln_kernel<<<NROWS, 256, 0, stream>>>(x, g1, be1, h_b);

    // Fused QKV GEMM: N = 3*1024, Bt = [wqT|wkT|wvT], SPLIT epilogue -> qb,kb,vb bf16
    gemm_bf16<true, false, false, false, true>
        <<<dim3(3 * EMB / 128, NROWS / 128), 256, 0, stream>>>(
            h_b, wqT, nullptr, nullptr, qb, NROWS, 3 * EMB, EMB);

    // MFMA flash attention -> bf16
    attn_mfma<<<dim3(SEQ / 64, NBATCH * NHEAD), 256, 0, stream>>>(qb, kb, vb, attnb);

    // Proj GEMM + bias + residual(x) -> x1 fp32
    gemm_bf16<false, false, true, true, false>
        <<<dim3(EMB / 128, NROWS / 128), 256, 0, stream>>>(
            attnb, wpT, b_proj, x, x1, NROWS, EMB, EMB);

    // LN2 -> bf16
    ln_kernel<<<NROWS, 256, 0, stream>>>(x1, g2, be2, h2b);

    // FF1 + bias + relu -> bf16
    gemm_bf16<true, true, true, false, false>
        <<<dim3(4 * EMB / 128, NROWS / 128), 256, 0, stream>>>(
            h2b, w1T, b1, nullptr, ffhb, NROWS, 4 * EMB, EMB);

    // FF2 + bias + residual(x1) -> out fp32
    gemm_bf16<false, false, true, true, false>
        <<<dim3(EMB / 128, NROWS / 128), 256, 0, stream>>>(
            ffhb, w2T, b2, x1, out, NROWS, EMB, 4 * EMB);
}

// Round 10
// 467.153 us; speedup vs baseline: 1.1054x; 1.1054x over previous
//
#include <hip/hip_runtime.h>
#include <hip/hip_bf16.h>

#define EMB 1024
#define HSZ 64
#define NHEAD 16
#define SEQ 2048
#define NBATCH 2
#define NROWS (NBATCH * SEQ) // 4096

using short8 = __attribute__((ext_vector_type(8))) short;
using f32x4  = __attribute__((ext_vector_type(4))) float;

__device__ __forceinline__ unsigned short f2b(float f) {
    __hip_bfloat16 b = __float2bfloat16(f);
    return *reinterpret_cast<unsigned short*>(&b);
}

// ---------------- LayerNorm: one block per row, bf16 out ----------------
__global__ __launch_bounds__(256) void ln_kernel(const float* __restrict__ x,
                                                 const float* __restrict__ g,
                                                 const float* __restrict__ b,
                                                 unsigned short* __restrict__ out) {
    int row = blockIdx.x;
    int t = threadIdx.x;
    const float* xr = x + (size_t)row * EMB;
    float v[4];
    float s = 0.f, s2 = 0.f;
#pragma unroll
    for (int i = 0; i < 4; ++i) {
        v[i] = xr[t + i * 256];
        s += v[i];
        s2 += v[i] * v[i];
    }
#pragma unroll
    for (int off = 1; off < 64; off <<= 1) {
        s += __shfl_xor(s, off);
        s2 += __shfl_xor(s2, off);
    }
    __shared__ float aux[8];
    int wave = t >> 6, lane = t & 63;
    if (lane == 0) { aux[wave] = s; aux[4 + wave] = s2; }
    __syncthreads();
    s = aux[0] + aux[1] + aux[2] + aux[3];
    s2 = aux[4] + aux[5] + aux[6] + aux[7];
    float mu = s * (1.f / EMB);
    float var = s2 * (1.f / EMB) - mu * mu;
    float r = rsqrtf(var + 1e-5f);
    unsigned short* orow = out + (size_t)row * EMB;
#pragma unroll
    for (int i = 0; i < 4; ++i) {
        int c = t + i * 256;
        orow[c] = f2b((v[i] - mu) * r * g[c] + b[c]);
    }
}

// ---------------- Transpose + fp32->bf16 convert ----------------
// in: K x N fp32 row-major (+ z*K*N), out: N x K bf16 row-major (+ z*N*K).
__global__ __launch_bounds__(256) void transpose_to_bf16(const float* __restrict__ in,
                                                         unsigned short* __restrict__ out,
                                                         int K, int N) {
    in  += (size_t)blockIdx.z * K * N;
    out += (size_t)blockIdx.z * N * K;
    __shared__ float tile[32][33];
    int k0 = blockIdx.y * 32, n0 = blockIdx.x * 32;
    int t = threadIdx.x;
    int r = t >> 3, c4 = (t & 7) * 4;
    float4 v = *reinterpret_cast<const float4*>(&in[(size_t)(k0 + r) * N + n0 + c4]);
    tile[r][c4 + 0] = v.x; tile[r][c4 + 1] = v.y;
    tile[r][c4 + 2] = v.z; tile[r][c4 + 3] = v.w;
    __syncthreads();
    ushort4 o;
    o.x = f2b(tile[c4 + 0][r]);
    o.y = f2b(tile[c4 + 1][r]);
    o.z = f2b(tile[c4 + 2][r]);
    o.w = f2b(tile[c4 + 3][r]);
    *reinterpret_cast<ushort4*>(&out[(size_t)(n0 + r) * K + k0 + c4]) = o;
}

// ---------------- V transpose (bf16 -> bf16, per head) ----------------
// in vb: [B*T, H*64] ; out vT: [B*H, 64, T]  (vT[bh][d][t])
__global__ __launch_bounds__(256) void transpose_v(const unsigned short* __restrict__ vb,
                                                   unsigned short* __restrict__ vT) {
    int bh = blockIdx.z;
    int b = bh >> 4, h = bh & 15;
    int t0 = blockIdx.x * 32, d0 = blockIdx.y * 32;
    __shared__ unsigned short tile[32][40];
    int tt = threadIdx.x;
    int r = tt >> 3, c4 = (tt & 7) * 4;
    ushort4 vv = *reinterpret_cast<const ushort4*>(
        &vb[((size_t)b * SEQ + t0 + r) * EMB + h * HSZ + d0 + c4]);
    tile[r][c4 + 0] = vv.x; tile[r][c4 + 1] = vv.y;
    tile[r][c4 + 2] = vv.z; tile[r][c4 + 3] = vv.w;
    __syncthreads();
    ushort4 o;
    o.x = tile[c4 + 0][r]; o.y = tile[c4 + 1][r];
    o.z = tile[c4 + 2][r]; o.w = tile[c4 + 3][r];
    *reinterpret_cast<ushort4*>(
        &vT[(size_t)bh * (HSZ * SEQ) + (size_t)(d0 + r) * SEQ + t0 + c4]) = o;
}

// ---------------- bf16 MFMA GEMM (m97 structure) ----------------
// C[M,N] = A[M,K] @ Bt[N,K]^T  (+bias)(+resid)(relu?), A/Bt bf16, acc fp32.
// BM=BN=128, BK=32, 256 threads = 4 waves (2x2), each wave 64x64 = 4x4 mfma_16x16x32 frags.
// SPLIT: N = 3x1024 (QKV fused); column block selects sub-buffer at C + (c>>10)*M*1024.
template <bool OUT_BF16, bool RELU, bool BIAS, bool RESID, bool SPLIT>
__global__ __launch_bounds__(256) void gemm_bf16(
    const unsigned short* __restrict__ A, const unsigned short* __restrict__ Bt,
    const float* __restrict__ bias, const float* __restrict__ resid,
    void* __restrict__ Cv, int M, int N, int K) {
    __shared__ unsigned short As[128 * 32];
    __shared__ unsigned short Bs[128 * 32];
    int c0 = blockIdx.x * 128, r0 = blockIdx.y * 128;
    int tid = threadIdx.x;
    int w = tid >> 6, l = tid & 63;
    int wr = w >> 1, wc = w & 1;

    f32x4 zero = {0.f, 0.f, 0.f, 0.f};
    f32x4 acc[4][4];
#pragma unroll
    for (int i = 0; i < 4; ++i)
#pragma unroll
        for (int j = 0; j < 4; ++j) acc[i][j] = zero;

    const unsigned short* Ab = A + (size_t)r0 * K;
    const unsigned short* Bb = Bt + (size_t)c0 * K;
    int srow = w * 32 + (l >> 2);   // staging row within tile (plus i*16)
    int scol = (l & 3) * 8;         // staging element col (16B granule)

    for (int k0 = 0; k0 < K; k0 += 32) {
#pragma unroll
        for (int i = 0; i < 2; ++i) {
            __builtin_amdgcn_global_load_lds(
                (const __attribute__((address_space(1))) void*)(Ab + (size_t)(srow + i * 16) * K + k0 + scol),
                (__attribute__((address_space(3))) void*)(&As[(w * 32 + i * 16) * 32]),
                16, 0, 0);
            __builtin_amdgcn_global_load_lds(
                (const __attribute__((address_space(1))) void*)(Bb + (size_t)(srow + i * 16) * K + k0 + scol),
                (__attribute__((address_space(3))) void*)(&Bs[(w * 32 + i * 16) * 32]),
                16, 0, 0);
        }
        __syncthreads();
        short8 a[4], b[4];
#pragma unroll
        for (int mi = 0; mi < 4; ++mi)
            a[mi] = *reinterpret_cast<const short8*>(&As[(wr * 64 + mi * 16 + (l & 15)) * 32 + (l >> 4) * 8]);
#pragma unroll
        for (int ni = 0; ni < 4; ++ni)
            b[ni] = *reinterpret_cast<const short8*>(&Bs[(wc * 64 + ni * 16 + (l & 15)) * 32 + (l >> 4) * 8]);
#pragma unroll
        for (int mi = 0; mi < 4; ++mi)
#pragma unroll
            for (int ni = 0; ni < 4; ++ni)
                acc[mi][ni] = __builtin_amdgcn_mfma_f32_16x16x32_bf16(a[mi], b[ni], acc[mi][ni], 0, 0, 0);
        __syncthreads();
    }

    // Epilogue. C/D layout: col = lane&15, row = (lane>>4)*4 + reg  [m89 verified]
#pragma unroll
    for (int mi = 0; mi < 4; ++mi) {
#pragma unroll
        for (int r = 0; r < 4; ++r) {
            int row = r0 + wr * 64 + mi * 16 + (l >> 4) * 4 + r;
#pragma unroll
            for (int ni = 0; ni < 4; ++ni) {
                int colg = c0 + wc * 64 + ni * 16 + (l & 15);
                float v = acc[mi][ni][r];
                if (BIAS) v += bias[colg];
                if (RESID) v += resid[(size_t)row * N + colg];
                if (RELU) v = fmaxf(v, 0.f);
                size_t coff;
                if (SPLIT)
                    coff = (size_t)(colg >> 10) * (size_t)M * 1024 + (size_t)row * 1024 + (colg & 1023);
                else
                    coff = (size_t)row * N + colg;
                if (OUT_BF16) ((unsigned short*)Cv)[coff] = f2b(v);
                else          ((float*)Cv)[coff] = v;
            }
        }
    }
}

// ---------------- MFMA flash attention (bf16 in/out, causal) ----------------
// q,k bf16 [B*T, H*HS]; vT bf16 [B*H, 64, T] (pre-transposed); o bf16 like q.
// Scale = 1/32. Block: 256 thr = 4 waves; Q-tile 64 rows; wave w owns rows w*16..+15.
// All LDS tiles row-padded to 72 shorts; every access is b128 (start-bank 4(r+s)
// pattern = conflict-free minimum, same as GEMM staging).
__global__ __launch_bounds__(256) void attn_mfma(const unsigned short* __restrict__ q,
                                                 const unsigned short* __restrict__ k,
                                                 const unsigned short* __restrict__ vT,
                                                 unsigned short* __restrict__ o) {
    int qt = blockIdx.x;
    int bh = blockIdx.y;
    int b = bh >> 4, h = bh & 15;
    const size_t base = (size_t)b * SEQ * EMB + (size_t)h * HSZ;
    const size_t vtb  = (size_t)bh * (HSZ * SEQ);
    __shared__ __align__(16) unsigned short Qs[64 * 72];
    __shared__ __align__(16) unsigned short Ks[64 * 72];
    __shared__ __align__(16) unsigned short Vs[64 * 72]; // [d][kv] (V^T tile)
    __shared__ __align__(16) unsigned short Ps[64 * 72];
    int tid = threadIdx.x, w = tid >> 6, l = tid & 63;
    int g = l >> 4, c = l & 15;

    // stage Q tile [64][64]
    for (int i = tid; i < 512; i += 256) {
        int r = i >> 3, s = i & 7;
        short8 t = *reinterpret_cast<const short8*>(&q[base + (size_t)(qt * 64 + r) * EMB + s * 8]);
        *reinterpret_cast<short8*>(&Qs[r * 72 + s * 8]) = t;
    }
    __syncthreads();
    short8 aq[2]; // Q A-frags, hoisted (rows w*16+c, dims kk*32 + g*8 ..+7)
    aq[0] = *reinterpret_cast<const short8*>(&Qs[(w * 16 + c) * 72 + g * 8]);
    aq[1] = *reinterpret_cast<const short8*>(&Qs[(w * 16 + c) * 72 + 32 + g * 8]);

    float m[4], lsum[4];
    f32x4 oacc[4];
    f32x4 zero = {0.f, 0.f, 0.f, 0.f};
#pragma unroll
    for (int r = 0; r < 4; ++r) { m[r] = -1e30f; lsum[r] = 0.f; }
#pragma unroll
    for (int ni = 0; ni < 4; ++ni) oacc[ni] = zero;

    for (int kt = 0; kt <= qt; ++kt) {
        __syncthreads(); // prior-tile PV reads of Ks/Vs done
        for (int i = tid; i < 512; i += 256) {
            int r = i >> 3, s = i & 7;
            short8 tk = *reinterpret_cast<const short8*>(&k[base + (size_t)(kt * 64 + r) * EMB + s * 8]);
            *reinterpret_cast<short8*>(&Ks[r * 72 + s * 8]) = tk;
            // V^T tile: Vs[d][kv] <- vT[bh][d = r][kt*64 + kv = s*8..+7]
            short8 tv = *reinterpret_cast<const short8*>(&vT[vtb + (size_t)r * SEQ + kt * 64 + s * 8]);
            *reinterpret_cast<short8*>(&Vs[r * 72 + s * 8]) = tv;
        }
        __syncthreads();
        // QK^T: S[16 x 64] per wave
        f32x4 sacc[4];
#pragma unroll
        for (int ni = 0; ni < 4; ++ni) sacc[ni] = zero;
        __builtin_amdgcn_s_setprio(1);
#pragma unroll
        for (int ni = 0; ni < 4; ++ni) {
            short8 bk0 = *reinterpret_cast<const short8*>(&Ks[(ni * 16 + c) * 72 + g * 8]);
            sacc[ni] = __builtin_amdgcn_mfma_f32_16x16x32_bf16(aq[0], bk0, sacc[ni], 0, 0, 0);
            short8 bk1 = *reinterpret_cast<const short8*>(&Ks[(ni * 16 + c) * 72 + 32 + g * 8]);
            sacc[ni] = __builtin_amdgcn_mfma_f32_16x16x32_bf16(aq[1], bk1, sacc[ni], 0, 0, 0);
        }
        __builtin_amdgcn_s_setprio(0);
        // online softmax; C layout: lane holds rows g*4+r, col ni*16+c
#pragma unroll
        for (int r = 0; r < 4; ++r) {
            int grow = w * 16 + g * 4 + r; // row within 64-row Q tile
            float sv[4];
            float rmax = -1e30f;
#pragma unroll
            for (int ni = 0; ni < 4; ++ni) {
                float s0 = sacc[ni][r] * 0.03125f;
                if (kt == qt && (ni * 16 + c) > grow) s0 = -1e30f;
                sv[ni] = s0;
                rmax = fmaxf(rmax, s0);
            }
#pragma unroll
            for (int off = 1; off < 16; off <<= 1) rmax = fmaxf(rmax, __shfl_xor(rmax, off));
            float mnew = fmaxf(m[r], rmax);
            float sc = __expf(m[r] - mnew);
            float ps = 0.f;
#pragma unroll
            for (int ni = 0; ni < 4; ++ni) {
                float p = __expf(sv[ni] - mnew);
                ps += p;
                Ps[grow * 72 + ni * 16 + c] = f2b(p);
            }
#pragma unroll
            for (int off = 1; off < 16; off <<= 1) ps += __shfl_xor(ps, off);
            lsum[r] = lsum[r] * sc + ps;
            m[r] = mnew;
#pragma unroll
            for (int ni = 0; ni < 4; ++ni) oacc[ni][r] *= sc;
        }
        __syncthreads(); // Ps visible
        // PV: O[16 x 64] += P[16 x 64] @ V[64 x 64]; B-frag = Vs row d, contiguous kv
        __builtin_amdgcn_s_setprio(1);
#pragma unroll
        for (int kk = 0; kk < 2; ++kk) {
            short8 ap = *reinterpret_cast<const short8*>(&Ps[(w * 16 + c) * 72 + kk * 32 + g * 8]);
#pragma unroll
            for (int ni = 0; ni < 4; ++ni) {
                short8 bv = *reinterpret_cast<const short8*>(&Vs[(ni * 16 + c) * 72 + kk * 32 + g * 8]);
                oacc[ni] = __builtin_amdgcn_mfma_f32_16x16x32_bf16(ap, bv, oacc[ni], 0, 0, 0);
            }
        }
        __builtin_amdgcn_s_setprio(0);
    }
#pragma unroll
    for (int r = 0; r < 4; ++r) {
        float inv = 1.f / lsum[r];
        size_t ro = base + (size_t)(qt * 64 + w * 16 + g * 4 + r) * EMB;
#pragma unroll
        for (int ni = 0; ni < 4; ++ni)
            o[ro + ni * 16 + c] = f2b(oacc[ni][r] * inv);
    }
}

extern "C" void kernel_launch(void* const* d_in, const int* in_sizes, int n_in,
                              void* d_out, int out_size, void* d_ws, size_t ws_size,
                              hipStream_t stream) {
    const float* x      = (const float*)d_in[0];
    const float* wq     = (const float*)d_in[1];
    const float* wk     = (const float*)d_in[2];
    const float* wv     = (const float*)d_in[3];
    const float* w_proj = (const float*)d_in[4];
    const float* b_proj = (const float*)d_in[5];
    const float* w1     = (const float*)d_in[6];
    const float* b1     = (const float*)d_in[7];
    const float* w2     = (const float*)d_in[8];
    const float* b2     = (const float*)d_in[9];
    const float* g1     = (const float*)d_in[10];
    const float* be1    = (const float*)d_in[11];
    const float* g2     = (const float*)d_in[12];
    const float* be2    = (const float*)d_in[13];
    float* out = (float*)d_out;

    const size_t MB = 1u << 20;
    char* w8 = (char*)d_ws;
    // Workspace plan (80 MB), phase-aliased:
    //  [0,16)   vT bf16 [B*H][64][2048] (dead after attn) -> x1 fp32 (proj out)
    //  [16,24)  h_b bf16 (LN1 out; dead after QKV) -> h2b (LN2 out)
    //  [24,32)  qb bf16 \
    //  [32,40)  kb bf16  > dead after attention -> ffhb [24,56) 32MB
    //  [40,48)  vb bf16 /
    //  [48,56)  attnb bf16 (dead after proj)
    //  [56,64)  wqT,wkT,wvT,wpT (2MB each; qkv contiguous)
    //  [64,72)  w1T   [72,80) w2T
    unsigned short* vTb   = (unsigned short*)(w8 + 0);
    float*          x1    = (float*)(w8 + 0);
    unsigned short* h_b   = (unsigned short*)(w8 + 16 * MB);
    unsigned short* h2b   = (unsigned short*)(w8 + 16 * MB);
    unsigned short* qb    = (unsigned short*)(w8 + 24 * MB);
    unsigned short* attnb = (unsigned short*)(w8 + 48 * MB);
    unsigned short* ffhb  = (unsigned short*)(w8 + 24 * MB);
    unsigned short* wqT   = (unsigned short*)(w8 + 56 * MB);
    unsigned short* wpT   = (unsigned short*)(w8 + 62 * MB);
    unsigned short* w1T   = (unsigned short*)(w8 + 64 * MB);
    unsigned short* w2T   = (unsigned short*)(w8 + 72 * MB);
    unsigned short* kb    = qb + (size_t)NROWS * EMB;
    unsigned short* vb    = kb + (size_t)NROWS * EMB;
    unsigned short* wkT   = wqT + (size_t)EMB * EMB;
    unsigned short* wvT   = wkT + (size_t)EMB * EMB;

    // Weight prep: transpose+convert to bf16 N x K ("B^T" form).
    transpose_to_bf16<<<dim3(2, 32, 16), 256, 0, stream>>>(wq, wqT, EMB, HSZ);
    transpose_to_bf16<<<dim3(2, 32, 16), 256, 0, stream>>>(wk, wkT, EMB, HSZ);
    transpose_to_bf16<<<dim3(2, 32, 16), 256, 0, stream>>>(wv, wvT, EMB, HSZ);
    transpose_to_bf16<<<dim3(32, 32, 1), 256, 0, stream>>>(w_proj, wpT, EMB, EMB);
    transpose_to_bf16<<<dim3(128, 32, 1), 256, 0, stream>>>(w1, w1T, EMB, 4 * EMB);
    transpose_to_bf16<<<dim3(32, 128, 1), 256, 0, stream>>>(w2, w2T, 4 * EMB, EMB);

    // LN1 -> bf16
    ln_kernel<<<NROWS, 256, 0, stream>>>(x, g1, be1, h_b);

    // Fused QKV GEMM: N = 3*1024, Bt = [wqT|wkT|wvT], SPLIT epilogue -> qb,kb,vb bf16
    gemm_bf16<true, false, false, false, true>
        <<<dim3(3 * EMB / 128, NROWS / 128), 256, 0, stream>>>(
            h_b, wqT, nullptr, nullptr, qb, NROWS, 3 * EMB, EMB);

    // V -> V^T per head (vT[bh][d][t])
    transpose_v<<<dim3(SEQ / 32, HSZ / 32, NBATCH * NHEAD), 256, 0, stream>>>(vb, vTb);

    // MFMA flash attention -> bf16
    attn_mfma<<<dim3(SEQ / 64, NBATCH * NHEAD), 256, 0, stream>>>(qb, kb, vTb, attnb);

    // Proj GEMM + bias + residual(x) -> x1 fp32  (overwrites vT region, attn is done)
    gemm_bf16<false, false, true, true, false>
        <<<dim3(EMB / 128, NROWS / 128), 256, 0, stream>>>(
            attnb, wpT, b_proj, x, x1, NROWS, EMB, EMB);

    // LN2 -> bf16
    ln_kernel<<<NROWS, 256, 0, stream>>>(x1, g2, be2, h2b);

    // FF1 + bias + relu -> bf16
    gemm_bf16<true, true, true, false, false>
        <<<dim3(4 * EMB / 128, NROWS / 128), 256, 0, stream>>>(
            h2b, w1T, b1, nullptr, ffhb, NROWS, 4 * EMB, EMB);

    // FF2 + bias + residual(x1) -> out fp32
    gemm_bf16<false, false, true, true, false>
        <<<dim3(EMB / 128, NROWS / 128), 256, 0, stream>>>(
            ffhb, w2T, b2, x1, out, NROWS, EMB, 4 * EMB);
}

// Round 11
// 449.610 us; speedup vs baseline: 1.1485x; 1.0390x over previous
//
#include <hip/hip_runtime.h>
#include <hip/hip_bf16.h>

#define EMB 1024
#define HSZ 64
#define NHEAD 16
#define SEQ 2048
#define NBATCH 2
#define NROWS (NBATCH * SEQ) // 4096

using short8 = __attribute__((ext_vector_type(8))) short;
using f32x4  = __attribute__((ext_vector_type(4))) float;

__device__ __forceinline__ unsigned short f2b(float f) {
    __hip_bfloat16 b = __float2bfloat16(f);
    return *reinterpret_cast<unsigned short*>(&b);
}

// ---------------- LayerNorm: one block per row, bf16 out ----------------
__global__ __launch_bounds__(256) void ln_kernel(const float* __restrict__ x,
                                                 const float* __restrict__ g,
                                                 const float* __restrict__ b,
                                                 unsigned short* __restrict__ out) {
    int row = blockIdx.x;
    int t = threadIdx.x;
    const float* xr = x + (size_t)row * EMB;
    float v[4];
    float s = 0.f, s2 = 0.f;
#pragma unroll
    for (int i = 0; i < 4; ++i) {
        v[i] = xr[t + i * 256];
        s += v[i];
        s2 += v[i] * v[i];
    }
#pragma unroll
    for (int off = 1; off < 64; off <<= 1) {
        s += __shfl_xor(s, off);
        s2 += __shfl_xor(s2, off);
    }
    __shared__ float aux[8];
    int wave = t >> 6, lane = t & 63;
    if (lane == 0) { aux[wave] = s; aux[4 + wave] = s2; }
    __syncthreads();
    s = aux[0] + aux[1] + aux[2] + aux[3];
    s2 = aux[4] + aux[5] + aux[6] + aux[7];
    float mu = s * (1.f / EMB);
    float var = s2 * (1.f / EMB) - mu * mu;
    float r = rsqrtf(var + 1e-5f);
    unsigned short* orow = out + (size_t)row * EMB;
#pragma unroll
    for (int i = 0; i < 4; ++i) {
        int c = t + i * 256;
        orow[c] = f2b((v[i] - mu) * r * g[c] + b[c]);
    }
}

// ---------------- Transpose + fp32->bf16 convert ----------------
// in: K x N fp32 row-major (+ z*K*N), out: N x K bf16 row-major (+ z*N*K).
__global__ __launch_bounds__(256) void transpose_to_bf16(const float* __restrict__ in,
                                                         unsigned short* __restrict__ out,
                                                         int K, int N) {
    in  += (size_t)blockIdx.z * K * N;
    out += (size_t)blockIdx.z * N * K;
    __shared__ float tile[32][33];
    int k0 = blockIdx.y * 32, n0 = blockIdx.x * 32;
    int t = threadIdx.x;
    int r = t >> 3, c4 = (t & 7) * 4;
    float4 v = *reinterpret_cast<const float4*>(&in[(size_t)(k0 + r) * N + n0 + c4]);
    tile[r][c4 + 0] = v.x; tile[r][c4 + 1] = v.y;
    tile[r][c4 + 2] = v.z; tile[r][c4 + 3] = v.w;
    __syncthreads();
    ushort4 o;
    o.x = f2b(tile[c4 + 0][r]);
    o.y = f2b(tile[c4 + 1][r]);
    o.z = f2b(tile[c4 + 2][r]);
    o.w = f2b(tile[c4 + 3][r]);
    *reinterpret_cast<ushort4*>(&out[(size_t)(n0 + r) * K + k0 + c4]) = o;
}

// ---------------- V transpose (bf16 -> bf16, per head) ----------------
// in vb: [B*T, H*64] ; out vT: [B*H, 64, T]  (vT[bh][d][t])
__global__ __launch_bounds__(256) void transpose_v(const unsigned short* __restrict__ vb,
                                                   unsigned short* __restrict__ vT) {
    int bh = blockIdx.z;
    int b = bh >> 4, h = bh & 15;
    int t0 = blockIdx.x * 32, d0 = blockIdx.y * 32;
    __shared__ unsigned short tile[32][40];
    int tt = threadIdx.x;
    int r = tt >> 3, c4 = (tt & 7) * 4;
    ushort4 vv = *reinterpret_cast<const ushort4*>(
        &vb[((size_t)b * SEQ + t0 + r) * EMB + h * HSZ + d0 + c4]);
    tile[r][c4 + 0] = vv.x; tile[r][c4 + 1] = vv.y;
    tile[r][c4 + 2] = vv.z; tile[r][c4 + 3] = vv.w;
    __syncthreads();
    ushort4 o;
    o.x = tile[c4 + 0][r]; o.y = tile[c4 + 1][r];
    o.z = tile[c4 + 2][r]; o.w = tile[c4 + 3][r];
    *reinterpret_cast<ushort4*>(
        &vT[(size_t)bh * (HSZ * SEQ) + (size_t)(d0 + r) * SEQ + t0 + c4]) = o;
}

// ---------------- bf16 MFMA GEMM (m97 structure, BN-templated) ----------------
// C[M,N] = A[M,K] @ Bt[N,K]^T  (+bias)(+resid)(relu?), A/Bt bf16, acc fp32.
// BM=128, BN in {64,128}, BK=32, 256 threads = 4 waves (2x2).
// Wave output: 64 x BN/2 (4 x BN/32 mfma_16x16x32 frags).
// BN=64 for N=1024 GEMMs: grid 512 blocks = 2 blocks/CU (vs 1 at BN=128).
// SPLIT (BN=128 only): QKV fused; col block selects sub-buffer at C + (c>>10)*M*1024.
template <int BN, bool OUT_BF16, bool RELU, bool BIAS, bool RESID, bool SPLIT>
__global__ __launch_bounds__(256) void gemm_bf16(
    const unsigned short* __restrict__ A, const unsigned short* __restrict__ Bt,
    const float* __restrict__ bias, const float* __restrict__ resid,
    void* __restrict__ Cv, int M, int N, int K) {
    constexpr int NI = BN / 32;  // B frags per wave
    __shared__ unsigned short As[128 * 32];
    __shared__ unsigned short Bs[BN * 32];
    int c0 = blockIdx.x * BN, r0 = blockIdx.y * 128;
    int tid = threadIdx.x;
    int w = tid >> 6, l = tid & 63;
    int wr = w >> 1, wc = w & 1;

    f32x4 zero = {0.f, 0.f, 0.f, 0.f};
    f32x4 acc[4][NI];
#pragma unroll
    for (int i = 0; i < 4; ++i)
#pragma unroll
        for (int j = 0; j < NI; ++j) acc[i][j] = zero;

    const unsigned short* Ab = A + (size_t)r0 * K;
    const unsigned short* Bb = Bt + (size_t)c0 * K;
    int srow = (l >> 2);            // +w*32 + i*16 for A rows
    int scol = (l & 3) * 8;         // staging element col (16B granule)

    for (int k0 = 0; k0 < K; k0 += 32) {
#pragma unroll
        for (int i = 0; i < 2; ++i) {
            __builtin_amdgcn_global_load_lds(
                (const __attribute__((address_space(1))) void*)(Ab + (size_t)(w * 32 + i * 16 + srow) * K + k0 + scol),
                (__attribute__((address_space(3))) void*)(&As[(w * 32 + i * 16) * 32]),
                16, 0, 0);
        }
#pragma unroll
        for (int i = 0; i < BN / 64; ++i) {
            __builtin_amdgcn_global_load_lds(
                (const __attribute__((address_space(1))) void*)(Bb + (size_t)(w * (BN / 4) + i * 16 + srow) * K + k0 + scol),
                (__attribute__((address_space(3))) void*)(&Bs[(w * (BN / 4) + i * 16) * 32]),
                16, 0, 0);
        }
        __syncthreads();
        short8 a[4], b[NI];
#pragma unroll
        for (int mi = 0; mi < 4; ++mi)
            a[mi] = *reinterpret_cast<const short8*>(&As[(wr * 64 + mi * 16 + (l & 15)) * 32 + (l >> 4) * 8]);
#pragma unroll
        for (int ni = 0; ni < NI; ++ni)
            b[ni] = *reinterpret_cast<const short8*>(&Bs[(wc * (BN / 2) + ni * 16 + (l & 15)) * 32 + (l >> 4) * 8]);
#pragma unroll
        for (int mi = 0; mi < 4; ++mi)
#pragma unroll
            for (int ni = 0; ni < NI; ++ni)
                acc[mi][ni] = __builtin_amdgcn_mfma_f32_16x16x32_bf16(a[mi], b[ni], acc[mi][ni], 0, 0, 0);
        __syncthreads();
    }

    // Epilogue. C/D layout: col = lane&15, row = (lane>>4)*4 + reg  [m89 verified]
#pragma unroll
    for (int mi = 0; mi < 4; ++mi) {
#pragma unroll
        for (int r = 0; r < 4; ++r) {
            int row = r0 + wr * 64 + mi * 16 + (l >> 4) * 4 + r;
#pragma unroll
            for (int ni = 0; ni < NI; ++ni) {
                int colg = c0 + wc * (BN / 2) + ni * 16 + (l & 15);
                float v = acc[mi][ni][r];
                if (BIAS) v += bias[colg];
                if (RESID) v += resid[(size_t)row * N + colg];
                if (RELU) v = fmaxf(v, 0.f);
                size_t coff;
                if (SPLIT)
                    coff = (size_t)(colg >> 10) * (size_t)M * 1024 + (size_t)row * 1024 + (colg & 1023);
                else
                    coff = (size_t)row * N + colg;
                if (OUT_BF16) ((unsigned short*)Cv)[coff] = f2b(v);
                else          ((float*)Cv)[coff] = v;
            }
        }
    }
}

// ---------------- MFMA flash attention (bf16 in/out, causal) ----------------
// q,k bf16 [B*T, H*HS]; vT bf16 [B*H, 64, T] (pre-transposed); o bf16 like q.
// Scale = 1/32. Block: 256 thr = 4 waves; Q-tile 64 rows; wave w owns rows w*16..+15.
// LPT schedule: qt = 31 - blockIdx.x so longest (most kv-tiles) blocks dispatch
// FIRST -> balanced CU packing, no tail (R10 counters: occupancy 19.5% from
// shortest-first imbalance). Blocks independent: reorder is correctness-free.
// All LDS tiles row-padded to 72 shorts; every access is b128.
__global__ __launch_bounds__(256) void attn_mfma(const unsigned short* __restrict__ q,
                                                 const unsigned short* __restrict__ k,
                                                 const unsigned short* __restrict__ vT,
                                                 unsigned short* __restrict__ o) {
    int qt = (SEQ / 64) - 1 - blockIdx.x;  // LPT: longest first
    int bh = blockIdx.y;
    int b = bh >> 4, h = bh & 15;
    const size_t base = (size_t)b * SEQ * EMB + (size_t)h * HSZ;
    const size_t vtb  = (size_t)bh * (HSZ * SEQ);
    __shared__ __align__(16) unsigned short Qs[64 * 72];
    __shared__ __align__(16) unsigned short Ks[64 * 72];
    __shared__ __align__(16) unsigned short Vs[64 * 72]; // [d][kv] (V^T tile)
    __shared__ __align__(16) unsigned short Ps[64 * 72];
    int tid = threadIdx.x, w = tid >> 6, l = tid & 63;
    int g = l >> 4, c = l & 15;

    // stage Q tile [64][64]
    for (int i = tid; i < 512; i += 256) {
        int r = i >> 3, s = i & 7;
        short8 t = *reinterpret_cast<const short8*>(&q[base + (size_t)(qt * 64 + r) * EMB + s * 8]);
        *reinterpret_cast<short8*>(&Qs[r * 72 + s * 8]) = t;
    }
    __syncthreads();
    short8 aq[2]; // Q A-frags, hoisted (rows w*16+c, dims kk*32 + g*8 ..+7)
    aq[0] = *reinterpret_cast<const short8*>(&Qs[(w * 16 + c) * 72 + g * 8]);
    aq[1] = *reinterpret_cast<const short8*>(&Qs[(w * 16 + c) * 72 + 32 + g * 8]);

    float m[4], lsum[4];
    f32x4 oacc[4];
    f32x4 zero = {0.f, 0.f, 0.f, 0.f};
#pragma unroll
    for (int r = 0; r < 4; ++r) { m[r] = -1e30f; lsum[r] = 0.f; }
#pragma unroll
    for (int ni = 0; ni < 4; ++ni) oacc[ni] = zero;

    for (int kt = 0; kt <= qt; ++kt) {
        __syncthreads(); // prior-tile PV reads of Ks/Vs done
        for (int i = tid; i < 512; i += 256) {
            int r = i >> 3, s = i & 7;
            short8 tk = *reinterpret_cast<const short8*>(&k[base + (size_t)(kt * 64 + r) * EMB + s * 8]);
            *reinterpret_cast<short8*>(&Ks[r * 72 + s * 8]) = tk;
            // V^T tile: Vs[d][kv] <- vT[bh][d = r][kt*64 + kv = s*8..+7]
            short8 tv = *reinterpret_cast<const short8*>(&vT[vtb + (size_t)r * SEQ + kt * 64 + s * 8]);
            *reinterpret_cast<short8*>(&Vs[r * 72 + s * 8]) = tv;
        }
        __syncthreads();
        // QK^T: S[16 x 64] per wave
        f32x4 sacc[4];
#pragma unroll
        for (int ni = 0; ni < 4; ++ni) sacc[ni] = zero;
        __builtin_amdgcn_s_setprio(1);
#pragma unroll
        for (int ni = 0; ni < 4; ++ni) {
            short8 bk0 = *reinterpret_cast<const short8*>(&Ks[(ni * 16 + c) * 72 + g * 8]);
            sacc[ni] = __builtin_amdgcn_mfma_f32_16x16x32_bf16(aq[0], bk0, sacc[ni], 0, 0, 0);
            short8 bk1 = *reinterpret_cast<const short8*>(&Ks[(ni * 16 + c) * 72 + 32 + g * 8]);
            sacc[ni] = __builtin_amdgcn_mfma_f32_16x16x32_bf16(aq[1], bk1, sacc[ni], 0, 0, 0);
        }
        __builtin_amdgcn_s_setprio(0);
        // online softmax; C layout: lane holds rows g*4+r, col ni*16+c
#pragma unroll
        for (int r = 0; r < 4; ++r) {
            int grow = w * 16 + g * 4 + r; // row within 64-row Q tile
            float sv[4];
            float rmax = -1e30f;
#pragma unroll
            for (int ni = 0; ni < 4; ++ni) {
                float s0 = sacc[ni][r] * 0.03125f;
                if (kt == qt && (ni * 16 + c) > grow) s0 = -1e30f;
                sv[ni] = s0;
                rmax = fmaxf(rmax, s0);
            }
#pragma unroll
            for (int off = 1; off < 16; off <<= 1) rmax = fmaxf(rmax, __shfl_xor(rmax, off));
            float mnew = fmaxf(m[r], rmax);
            float sc = __expf(m[r] - mnew);
            float ps = 0.f;
#pragma unroll
            for (int ni = 0; ni < 4; ++ni) {
                float p = __expf(sv[ni] - mnew);
                ps += p;
                Ps[grow * 72 + ni * 16 + c] = f2b(p);
            }
#pragma unroll
            for (int off = 1; off < 16; off <<= 1) ps += __shfl_xor(ps, off);
            lsum[r] = lsum[r] * sc + ps;
            m[r] = mnew;
#pragma unroll
            for (int ni = 0; ni < 4; ++ni) oacc[ni][r] *= sc;
        }
        __syncthreads(); // Ps visible
        // PV: O[16 x 64] += P[16 x 64] @ V[64 x 64]; B-frag = Vs row d, contiguous kv
        __builtin_amdgcn_s_setprio(1);
#pragma unroll
        for (int kk = 0; kk < 2; ++kk) {
            short8 ap = *reinterpret_cast<const short8*>(&Ps[(w * 16 + c) * 72 + kk * 32 + g * 8]);
#pragma unroll
            for (int ni = 0; ni < 4; ++ni) {
                short8 bv = *reinterpret_cast<const short8*>(&Vs[(ni * 16 + c) * 72 + kk * 32 + g * 8]);
                oacc[ni] = __builtin_amdgcn_mfma_f32_16x16x32_bf16(ap, bv, oacc[ni], 0, 0, 0);
            }
        }
        __builtin_amdgcn_s_setprio(0);
    }
#pragma unroll
    for (int r = 0; r < 4; ++r) {
        float inv = 1.f / lsum[r];
        size_t ro = base + (size_t)(qt * 64 + w * 16 + g * 4 + r) * EMB;
#pragma unroll
        for (int ni = 0; ni < 4; ++ni)
            o[ro + ni * 16 + c] = f2b(oacc[ni][r] * inv);
    }
}

extern "C" void kernel_launch(void* const* d_in, const int* in_sizes, int n_in,
                              void* d_out, int out_size, void* d_ws, size_t ws_size,
                              hipStream_t stream) {
    const float* x      = (const float*)d_in[0];
    const float* wq     = (const float*)d_in[1];
    const float* wk     = (const float*)d_in[2];
    const float* wv     = (const float*)d_in[3];
    const float* w_proj = (const float*)d_in[4];
    const float* b_proj = (const float*)d_in[5];
    const float* w1     = (const float*)d_in[6];
    const float* b1     = (const float*)d_in[7];
    const float* w2     = (const float*)d_in[8];
    const float* b2     = (const float*)d_in[9];
    const float* g1     = (const float*)d_in[10];
    const float* be1    = (const float*)d_in[11];
    const float* g2     = (const float*)d_in[12];
    const float* be2    = (const float*)d_in[13];
    float* out = (float*)d_out;

    const size_t MB = 1u << 20;
    char* w8 = (char*)d_ws;
    // Workspace plan (80 MB), phase-aliased:
    //  [0,16)   vT bf16 [B*H][64][2048] (dead after attn) -> x1 fp32 (proj out)
    //  [16,24)  h_b bf16 (LN1 out; dead after QKV) -> h2b (LN2 out)
    //  [24,32)  qb bf16 \
    //  [32,40)  kb bf16  > dead after attention -> ffhb [24,56) 32MB
    //  [40,48)  vb bf16 /
    //  [48,56)  attnb bf16 (dead after proj)
    //  [56,64)  wqT,wkT,wvT,wpT (2MB each; qkv contiguous)
    //  [64,72)  w1T   [72,80) w2T
    unsigned short* vTb   = (unsigned short*)(w8 + 0);
    float*          x1    = (float*)(w8 + 0);
    unsigned short* h_b   = (unsigned short*)(w8 + 16 * MB);
    unsigned short* h2b   = (unsigned short*)(w8 + 16 * MB);
    unsigned short* qb    = (unsigned short*)(w8 + 24 * MB);
    unsigned short* attnb = (unsigned short*)(w8 + 48 * MB);
    unsigned short* ffhb  = (unsigned short*)(w8 + 24 * MB);
    unsigned short* wqT   = (unsigned short*)(w8 + 56 * MB);
    unsigned short* wpT   = (unsigned short*)(w8 + 62 * MB);
    unsigned short* w1T   = (unsigned short*)(w8 + 64 * MB);
    unsigned short* w2T   = (unsigned short*)(w8 + 72 * MB);
    unsigned short* kb    = qb + (size_t)NROWS * EMB;
    unsigned short* vb    = kb + (size_t)NROWS * EMB;
    unsigned short* wkT   = wqT + (size_t)EMB * EMB;
    unsigned short* wvT   = wkT + (size_t)EMB * EMB;

    // Weight prep: transpose+convert to bf16 N x K ("B^T" form).
    transpose_to_bf16<<<dim3(2, 32, 16), 256, 0, stream>>>(wq, wqT, EMB, HSZ);
    transpose_to_bf16<<<dim3(2, 32, 16), 256, 0, stream>>>(wk, wkT, EMB, HSZ);
    transpose_to_bf16<<<dim3(2, 32, 16), 256, 0, stream>>>(wv, wvT, EMB, HSZ);
    transpose_to_bf16<<<dim3(32, 32, 1), 256, 0, stream>>>(w_proj, wpT, EMB, EMB);
    transpose_to_bf16<<<dim3(128, 32, 1), 256, 0, stream>>>(w1, w1T, EMB, 4 * EMB);
    transpose_to_bf16<<<dim3(32, 128, 1), 256, 0, stream>>>(w2, w2T, 4 * EMB, EMB);

    // LN1 -> bf16
    ln_kernel<<<NROWS, 256, 0, stream>>>(x, g1, be1, h_b);

    // Fused QKV GEMM: N = 3*1024, Bt = [wqT|wkT|wvT], SPLIT epilogue -> qb,kb,vb bf16
    gemm_bf16<128, true, false, false, false, true>
        <<<dim3(3 * EMB / 128, NROWS / 128), 256, 0, stream>>>(
            h_b, wqT, nullptr, nullptr, qb, NROWS, 3 * EMB, EMB);

    // V -> V^T per head (vT[bh][d][t])
    transpose_v<<<dim3(SEQ / 32, HSZ / 32, NBATCH * NHEAD), 256, 0, stream>>>(vb, vTb);

    // MFMA flash attention -> bf16
    attn_mfma<<<dim3(SEQ / 64, NBATCH * NHEAD), 256, 0, stream>>>(qb, kb, vTb, attnb);

    // Proj GEMM + bias + residual(x) -> x1 fp32  (BN=64: 512 blocks = 2/CU)
    gemm_bf16<64, false, false, true, true, false>
        <<<dim3(EMB / 64, NROWS / 128), 256, 0, stream>>>(
            attnb, wpT, b_proj, x, x1, NROWS, EMB, EMB);

    // LN2 -> bf16
    ln_kernel<<<NROWS, 256, 0, stream>>>(x1, g2, be2, h2b);

    // FF1 + bias + relu -> bf16
    gemm_bf16<128, true, true, true, false, false>
        <<<dim3(4 * EMB / 128, NROWS / 128), 256, 0, stream>>>(
            h2b, w1T, b1, nullptr, ffhb, NROWS, 4 * EMB, EMB);

    // FF2 + bias + residual(x1) -> out fp32  (BN=64: 512 blocks = 2/CU)
    gemm_bf16<64, false, false, true, true, false>
        <<<dim3(EMB / 64, NROWS / 128), 256, 0, stream>>>(
            ffhb, w2T, b2, x1, out, NROWS, EMB, 4 * EMB);
}

// Round 12
// 416.773 us; speedup vs baseline: 1.2390x; 1.0788x over previous
//
#include <hip/hip_runtime.h>
#include <hip/hip_bf16.h>

#define EMB 1024
#define HSZ 64
#define NHEAD 16
#define SEQ 2048
#define NBATCH 2
#define NROWS (NBATCH * SEQ) // 4096

using short8 = __attribute__((ext_vector_type(8))) short;
using f32x4  = __attribute__((ext_vector_type(4))) float;

__device__ __forceinline__ unsigned short f2b(float f) {
    __hip_bfloat16 b = __float2bfloat16(f);
    return *reinterpret_cast<unsigned short*>(&b);
}

// ---------------- LayerNorm: one block per row, bf16 out ----------------
__global__ __launch_bounds__(256) void ln_kernel(const float* __restrict__ x,
                                                 const float* __restrict__ g,
                                                 const float* __restrict__ b,
                                                 unsigned short* __restrict__ out) {
    int row = blockIdx.x;
    int t = threadIdx.x;
    const float* xr = x + (size_t)row * EMB;
    float v[4];
    float s = 0.f, s2 = 0.f;
#pragma unroll
    for (int i = 0; i < 4; ++i) {
        v[i] = xr[t + i * 256];
        s += v[i];
        s2 += v[i] * v[i];
    }
#pragma unroll
    for (int off = 1; off < 64; off <<= 1) {
        s += __shfl_xor(s, off);
        s2 += __shfl_xor(s2, off);
    }
    __shared__ float aux[8];
    int wave = t >> 6, lane = t & 63;
    if (lane == 0) { aux[wave] = s; aux[4 + wave] = s2; }
    __syncthreads();
    s = aux[0] + aux[1] + aux[2] + aux[3];
    s2 = aux[4] + aux[5] + aux[6] + aux[7];
    float mu = s * (1.f / EMB);
    float var = s2 * (1.f / EMB) - mu * mu;
    float r = rsqrtf(var + 1e-5f);
    unsigned short* orow = out + (size_t)row * EMB;
#pragma unroll
    for (int i = 0; i < 4; ++i) {
        int c = t + i * 256;
        orow[c] = f2b((v[i] - mu) * r * g[c] + b[c]);
    }
}

// ---------------- Transpose + fp32->bf16 convert ----------------
// in: K x N fp32 row-major (+ z*K*N), out: N x K bf16 row-major (+ z*N*K).
__global__ __launch_bounds__(256) void transpose_to_bf16(const float* __restrict__ in,
                                                         unsigned short* __restrict__ out,
                                                         int K, int N) {
    in  += (size_t)blockIdx.z * K * N;
    out += (size_t)blockIdx.z * N * K;
    __shared__ float tile[32][33];
    int k0 = blockIdx.y * 32, n0 = blockIdx.x * 32;
    int t = threadIdx.x;
    int r = t >> 3, c4 = (t & 7) * 4;
    float4 v = *reinterpret_cast<const float4*>(&in[(size_t)(k0 + r) * N + n0 + c4]);
    tile[r][c4 + 0] = v.x; tile[r][c4 + 1] = v.y;
    tile[r][c4 + 2] = v.z; tile[r][c4 + 3] = v.w;
    __syncthreads();
    ushort4 o;
    o.x = f2b(tile[c4 + 0][r]);
    o.y = f2b(tile[c4 + 1][r]);
    o.z = f2b(tile[c4 + 2][r]);
    o.w = f2b(tile[c4 + 3][r]);
    *reinterpret_cast<ushort4*>(&out[(size_t)(n0 + r) * K + k0 + c4]) = o;
}

// ---------------- V transpose (bf16 -> bf16, per head) ----------------
// in vb: [B*T, H*64] ; out vT: [B*H, 64, T]  (vT[bh][d][t])
__global__ __launch_bounds__(256) void transpose_v(const unsigned short* __restrict__ vb,
                                                   unsigned short* __restrict__ vT) {
    int bh = blockIdx.z;
    int b = bh >> 4, h = bh & 15;
    int t0 = blockIdx.x * 32, d0 = blockIdx.y * 32;
    __shared__ unsigned short tile[32][40];
    int tt = threadIdx.x;
    int r = tt >> 3, c4 = (tt & 7) * 4;
    ushort4 vv = *reinterpret_cast<const ushort4*>(
        &vb[((size_t)b * SEQ + t0 + r) * EMB + h * HSZ + d0 + c4]);
    tile[r][c4 + 0] = vv.x; tile[r][c4 + 1] = vv.y;
    tile[r][c4 + 2] = vv.z; tile[r][c4 + 3] = vv.w;
    __syncthreads();
    ushort4 o;
    o.x = tile[c4 + 0][r]; o.y = tile[c4 + 1][r];
    o.z = tile[c4 + 2][r]; o.w = tile[c4 + 3][r];
    *reinterpret_cast<ushort4*>(
        &vT[(size_t)bh * (HSZ * SEQ) + (size_t)(d0 + r) * SEQ + t0 + c4]) = o;
}

// ---------------- bf16 MFMA GEMM (m97 structure, BN-templated) ----------------
// C[M,N] = A[M,K] @ Bt[N,K]^T  (+bias)(+resid)(relu?), A/Bt bf16, acc fp32.
// BM=128, BN in {64,128}, BK=32, 256 threads = 4 waves (2x2).
// Wave output: 64 x BN/2 (4 x BN/32 mfma_16x16x32 frags).
// BN=64 for N=1024 GEMMs: grid 512 blocks = 2 blocks/CU (vs 1 at BN=128).
// SPLIT (BN=128 only): QKV fused; col block selects sub-buffer at C + (c>>10)*M*1024.
template <int BN, bool OUT_BF16, bool RELU, bool BIAS, bool RESID, bool SPLIT>
__global__ __launch_bounds__(256) void gemm_bf16(
    const unsigned short* __restrict__ A, const unsigned short* __restrict__ Bt,
    const float* __restrict__ bias, const float* __restrict__ resid,
    void* __restrict__ Cv, int M, int N, int K) {
    constexpr int NI = BN / 32;  // B frags per wave
    __shared__ unsigned short As[128 * 32];
    __shared__ unsigned short Bs[BN * 32];
    int c0 = blockIdx.x * BN, r0 = blockIdx.y * 128;
    int tid = threadIdx.x;
    int w = tid >> 6, l = tid & 63;
    int wr = w >> 1, wc = w & 1;

    f32x4 zero = {0.f, 0.f, 0.f, 0.f};
    f32x4 acc[4][NI];
#pragma unroll
    for (int i = 0; i < 4; ++i)
#pragma unroll
        for (int j = 0; j < NI; ++j) acc[i][j] = zero;

    const unsigned short* Ab = A + (size_t)r0 * K;
    const unsigned short* Bb = Bt + (size_t)c0 * K;
    int srow = (l >> 2);            // +w*32 + i*16 for A rows
    int scol = (l & 3) * 8;         // staging element col (16B granule)

    for (int k0 = 0; k0 < K; k0 += 32) {
#pragma unroll
        for (int i = 0; i < 2; ++i) {
            __builtin_amdgcn_global_load_lds(
                (const __attribute__((address_space(1))) void*)(Ab + (size_t)(w * 32 + i * 16 + srow) * K + k0 + scol),
                (__attribute__((address_space(3))) void*)(&As[(w * 32 + i * 16) * 32]),
                16, 0, 0);
        }
#pragma unroll
        for (int i = 0; i < BN / 64; ++i) {
            __builtin_amdgcn_global_load_lds(
                (const __attribute__((address_space(1))) void*)(Bb + (size_t)(w * (BN / 4) + i * 16 + srow) * K + k0 + scol),
                (__attribute__((address_space(3))) void*)(&Bs[(w * (BN / 4) + i * 16) * 32]),
                16, 0, 0);
        }
        __syncthreads();
        short8 a[4], b[NI];
#pragma unroll
        for (int mi = 0; mi < 4; ++mi)
            a[mi] = *reinterpret_cast<const short8*>(&As[(wr * 64 + mi * 16 + (l & 15)) * 32 + (l >> 4) * 8]);
#pragma unroll
        for (int ni = 0; ni < NI; ++ni)
            b[ni] = *reinterpret_cast<const short8*>(&Bs[(wc * (BN / 2) + ni * 16 + (l & 15)) * 32 + (l >> 4) * 8]);
#pragma unroll
        for (int mi = 0; mi < 4; ++mi)
#pragma unroll
            for (int ni = 0; ni < NI; ++ni)
                acc[mi][ni] = __builtin_amdgcn_mfma_f32_16x16x32_bf16(a[mi], b[ni], acc[mi][ni], 0, 0, 0);
        __syncthreads();
    }

    // Epilogue. C/D layout: col = lane&15, row = (lane>>4)*4 + reg  [m89 verified]
#pragma unroll
    for (int mi = 0; mi < 4; ++mi) {
#pragma unroll
        for (int r = 0; r < 4; ++r) {
            int row = r0 + wr * 64 + mi * 16 + (l >> 4) * 4 + r;
#pragma unroll
            for (int ni = 0; ni < NI; ++ni) {
                int colg = c0 + wc * (BN / 2) + ni * 16 + (l & 15);
                float v = acc[mi][ni][r];
                if (BIAS) v += bias[colg];
                if (RESID) v += resid[(size_t)row * N + colg];
                if (RELU) v = fmaxf(v, 0.f);
                size_t coff;
                if (SPLIT)
                    coff = (size_t)(colg >> 10) * (size_t)M * 1024 + (size_t)row * 1024 + (colg & 1023);
                else
                    coff = (size_t)row * N + colg;
                if (OUT_BF16) ((unsigned short*)Cv)[coff] = f2b(v);
                else          ((float*)Cv)[coff] = v;
            }
        }
    }
}

// ---------------- MFMA flash attention (bf16 in/out, causal) ----------------
// q,k bf16 [B*T, H*HS]; vT bf16 [B*H, 64, T] (pre-transposed); o bf16 like q.
// Scale = 1/32. Block: 256 thr = 4 waves; wave w owns rows w*16..+15 of each tile.
// WORK BALANCE (R11 post-mortem): with one q-tile/block, blocks sharing a CU get
// identical qt (linear ids differ by 256 -> same blockIdx.x) -> per-CU load 4(qt+1)
// in 4..128 vs 66 mean; qt reordering can't fix it. Instead each block processes
// the complementary PAIR (bx, 31-bx): exactly 33 kv-tile units per block ->
// uniform by construction, mapping-independent. Grid (16, 32).
// All LDS tiles row-padded to 72 shorts; every access is b128.
__global__ __launch_bounds__(256) void attn_mfma(const unsigned short* __restrict__ q,
                                                 const unsigned short* __restrict__ k,
                                                 const unsigned short* __restrict__ vT,
                                                 unsigned short* __restrict__ o) {
    int bx = blockIdx.x;                   // 0..15
    int bh = blockIdx.y;
    int b = bh >> 4, h = bh & 15;
    const size_t base = (size_t)b * SEQ * EMB + (size_t)h * HSZ;
    const size_t vtb  = (size_t)bh * (HSZ * SEQ);
    __shared__ __align__(16) unsigned short Qs[64 * 72];
    __shared__ __align__(16) unsigned short Ks[64 * 72];
    __shared__ __align__(16) unsigned short Vs[64 * 72]; // [d][kv] (V^T tile)
    __shared__ __align__(16) unsigned short Ps[64 * 72];
    int tid = threadIdx.x, w = tid >> 6, l = tid & 63;
    int g = l >> 4, c = l & 15;

    for (int half = 0; half < 2; ++half) {
        int qt = half ? (SEQ / 64 - 1 - bx) : bx;

        // stage Q tile [64][64] (Qs not read in PV; kv-loop top barrier fences laggards)
        for (int i = tid; i < 512; i += 256) {
            int r = i >> 3, s = i & 7;
            short8 t = *reinterpret_cast<const short8*>(&q[base + (size_t)(qt * 64 + r) * EMB + s * 8]);
            *reinterpret_cast<short8*>(&Qs[r * 72 + s * 8]) = t;
        }
        __syncthreads();
        short8 aq[2]; // Q A-frags, hoisted (rows w*16+c, dims kk*32 + g*8 ..+7)
        aq[0] = *reinterpret_cast<const short8*>(&Qs[(w * 16 + c) * 72 + g * 8]);
        aq[1] = *reinterpret_cast<const short8*>(&Qs[(w * 16 + c) * 72 + 32 + g * 8]);

        float m[4], lsum[4];
        f32x4 oacc[4];
        f32x4 zero = {0.f, 0.f, 0.f, 0.f};
#pragma unroll
        for (int r = 0; r < 4; ++r) { m[r] = -1e30f; lsum[r] = 0.f; }
#pragma unroll
        for (int ni = 0; ni < 4; ++ni) oacc[ni] = zero;

        for (int kt = 0; kt <= qt; ++kt) {
            __syncthreads(); // prior-tile PV reads of Ks/Vs done
            for (int i = tid; i < 512; i += 256) {
                int r = i >> 3, s = i & 7;
                short8 tk = *reinterpret_cast<const short8*>(&k[base + (size_t)(kt * 64 + r) * EMB + s * 8]);
                *reinterpret_cast<short8*>(&Ks[r * 72 + s * 8]) = tk;
                // V^T tile: Vs[d][kv] <- vT[bh][d = r][kt*64 + kv = s*8..+7]
                short8 tv = *reinterpret_cast<const short8*>(&vT[vtb + (size_t)r * SEQ + kt * 64 + s * 8]);
                *reinterpret_cast<short8*>(&Vs[r * 72 + s * 8]) = tv;
            }
            __syncthreads();
            // QK^T: S[16 x 64] per wave
            f32x4 sacc[4];
#pragma unroll
            for (int ni = 0; ni < 4; ++ni) sacc[ni] = zero;
            __builtin_amdgcn_s_setprio(1);
#pragma unroll
            for (int ni = 0; ni < 4; ++ni) {
                short8 bk0 = *reinterpret_cast<const short8*>(&Ks[(ni * 16 + c) * 72 + g * 8]);
                sacc[ni] = __builtin_amdgcn_mfma_f32_16x16x32_bf16(aq[0], bk0, sacc[ni], 0, 0, 0);
                short8 bk1 = *reinterpret_cast<const short8*>(&Ks[(ni * 16 + c) * 72 + 32 + g * 8]);
                sacc[ni] = __builtin_amdgcn_mfma_f32_16x16x32_bf16(aq[1], bk1, sacc[ni], 0, 0, 0);
            }
            __builtin_amdgcn_s_setprio(0);
            // online softmax; C layout: lane holds rows g*4+r, col ni*16+c
#pragma unroll
            for (int r = 0; r < 4; ++r) {
                int grow = w * 16 + g * 4 + r; // row within 64-row Q tile
                float sv[4];
                float rmax = -1e30f;
#pragma unroll
                for (int ni = 0; ni < 4; ++ni) {
                    float s0 = sacc[ni][r] * 0.03125f;
                    if (kt == qt && (ni * 16 + c) > grow) s0 = -1e30f;
                    sv[ni] = s0;
                    rmax = fmaxf(rmax, s0);
                }
#pragma unroll
                for (int off = 1; off < 16; off <<= 1) rmax = fmaxf(rmax, __shfl_xor(rmax, off));
                float mnew = fmaxf(m[r], rmax);
                float sc = __expf(m[r] - mnew);
                float ps = 0.f;
#pragma unroll
                for (int ni = 0; ni < 4; ++ni) {
                    float p = __expf(sv[ni] - mnew);
                    ps += p;
                    Ps[grow * 72 + ni * 16 + c] = f2b(p);
                }
#pragma unroll
                for (int off = 1; off < 16; off <<= 1) ps += __shfl_xor(ps, off);
                lsum[r] = lsum[r] * sc + ps;
                m[r] = mnew;
#pragma unroll
                for (int ni = 0; ni < 4; ++ni) oacc[ni][r] *= sc;
            }
            __syncthreads(); // Ps visible
            // PV: O[16 x 64] += P[16 x 64] @ V[64 x 64]; B-frag = Vs row d, contiguous kv
            __builtin_amdgcn_s_setprio(1);
#pragma unroll
            for (int kk = 0; kk < 2; ++kk) {
                short8 ap = *reinterpret_cast<const short8*>(&Ps[(w * 16 + c) * 72 + kk * 32 + g * 8]);
#pragma unroll
                for (int ni = 0; ni < 4; ++ni) {
                    short8 bv = *reinterpret_cast<const short8*>(&Vs[(ni * 16 + c) * 72 + kk * 32 + g * 8]);
                    oacc[ni] = __builtin_amdgcn_mfma_f32_16x16x32_bf16(ap, bv, oacc[ni], 0, 0, 0);
                }
            }
            __builtin_amdgcn_s_setprio(0);
        }
#pragma unroll
        for (int r = 0; r < 4; ++r) {
            float inv = 1.f / lsum[r];
            size_t ro = base + (size_t)(qt * 64 + w * 16 + g * 4 + r) * EMB;
#pragma unroll
            for (int ni = 0; ni < 4; ++ni)
                o[ro + ni * 16 + c] = f2b(oacc[ni][r] * inv);
        }
    }
}

extern "C" void kernel_launch(void* const* d_in, const int* in_sizes, int n_in,
                              void* d_out, int out_size, void* d_ws, size_t ws_size,
                              hipStream_t stream) {
    const float* x      = (const float*)d_in[0];
    const float* wq     = (const float*)d_in[1];
    const float* wk     = (const float*)d_in[2];
    const float* wv     = (const float*)d_in[3];
    const float* w_proj = (const float*)d_in[4];
    const float* b_proj = (const float*)d_in[5];
    const float* w1     = (const float*)d_in[6];
    const float* b1     = (const float*)d_in[7];
    const float* w2     = (const float*)d_in[8];
    const float* b2     = (const float*)d_in[9];
    const float* g1     = (const float*)d_in[10];
    const float* be1    = (const float*)d_in[11];
    const float* g2     = (const float*)d_in[12];
    const float* be2    = (const float*)d_in[13];
    float* out = (float*)d_out;

    const size_t MB = 1u << 20;
    char* w8 = (char*)d_ws;
    // Workspace plan (80 MB), phase-aliased:
    //  [0,16)   vT bf16 [B*H][64][2048] (dead after attn) -> x1 fp32 (proj out)
    //  [16,24)  h_b bf16 (LN1 out; dead after QKV) -> h2b (LN2 out)
    //  [24,32)  qb bf16 \
    //  [32,40)  kb bf16  > dead after attention -> ffhb [24,56) 32MB
    //  [40,48)  vb bf16 /
    //  [48,56)  attnb bf16 (dead after proj)
    //  [56,64)  wqT,wkT,wvT,wpT (2MB each; qkv contiguous)
    //  [64,72)  w1T   [72,80) w2T
    unsigned short* vTb   = (unsigned short*)(w8 + 0);
    float*          x1    = (float*)(w8 + 0);
    unsigned short* h_b   = (unsigned short*)(w8 + 16 * MB);
    unsigned short* h2b   = (unsigned short*)(w8 + 16 * MB);
    unsigned short* qb    = (unsigned short*)(w8 + 24 * MB);
    unsigned short* attnb = (unsigned short*)(w8 + 48 * MB);
    unsigned short* ffhb  = (unsigned short*)(w8 + 24 * MB);
    unsigned short* wqT   = (unsigned short*)(w8 + 56 * MB);
    unsigned short* wpT   = (unsigned short*)(w8 + 62 * MB);
    unsigned short* w1T   = (unsigned short*)(w8 + 64 * MB);
    unsigned short* w2T   = (unsigned short*)(w8 + 72 * MB);
    unsigned short* kb    = qb + (size_t)NROWS * EMB;
    unsigned short* vb    = kb + (size_t)NROWS * EMB;
    unsigned short* wkT   = wqT + (size_t)EMB * EMB;
    unsigned short* wvT   = wkT + (size_t)EMB * EMB;

    // Weight prep: transpose+convert to bf16 N x K ("B^T" form).
    transpose_to_bf16<<<dim3(2, 32, 16), 256, 0, stream>>>(wq, wqT, EMB, HSZ);
    transpose_to_bf16<<<dim3(2, 32, 16), 256, 0, stream>>>(wk, wkT, EMB, HSZ);
    transpose_to_bf16<<<dim3(2, 32, 16), 256, 0, stream>>>(wv, wvT, EMB, HSZ);
    transpose_to_bf16<<<dim3(32, 32, 1), 256, 0, stream>>>(w_proj, wpT, EMB, EMB);
    transpose_to_bf16<<<dim3(128, 32, 1), 256, 0, stream>>>(w1, w1T, EMB, 4 * EMB);
    transpose_to_bf16<<<dim3(32, 128, 1), 256, 0, stream>>>(w2, w2T, 4 * EMB, EMB);

    // LN1 -> bf16
    ln_kernel<<<NROWS, 256, 0, stream>>>(x, g1, be1, h_b);

    // Fused QKV GEMM: N = 3*1024, Bt = [wqT|wkT|wvT], SPLIT epilogue -> qb,kb,vb bf16
    gemm_bf16<128, true, false, false, false, true>
        <<<dim3(3 * EMB / 128, NROWS / 128), 256, 0, stream>>>(
            h_b, wqT, nullptr, nullptr, qb, NROWS, 3 * EMB, EMB);

    // V -> V^T per head (vT[bh][d][t])
    transpose_v<<<dim3(SEQ / 32, HSZ / 32, NBATCH * NHEAD), 256, 0, stream>>>(vb, vTb);

    // MFMA flash attention -> bf16 (paired q-tiles: grid x = SEQ/128)
    attn_mfma<<<dim3(SEQ / 128, NBATCH * NHEAD), 256, 0, stream>>>(qb, kb, vTb, attnb);

    // Proj GEMM + bias + residual(x) -> x1 fp32  (BN=64: 512 blocks = 2/CU)
    gemm_bf16<64, false, false, true, true, false>
        <<<dim3(EMB / 64, NROWS / 128), 256, 0, stream>>>(
            attnb, wpT, b_proj, x, x1, NROWS, EMB, EMB);

    // LN2 -> bf16
    ln_kernel<<<NROWS, 256, 0, stream>>>(x1, g2, be2, h2b);

    // FF1 + bias + relu -> bf16
    gemm_bf16<128, true, true, true, false, false>
        <<<dim3(4 * EMB / 128, NROWS / 128), 256, 0, stream>>>(
            h2b, w1T, b1, nullptr, ffhb, NROWS, 4 * EMB, EMB);

    // FF2 + bias + residual(x1) -> out fp32  (BN=64: 512 blocks = 2/CU)
    gemm_bf16<64, false, false, true, true, false>
        <<<dim3(EMB / 64, NROWS / 128), 256, 0, stream>>>(
            ffhb, w2T, b2, x1, out, NROWS, EMB, 4 * EMB);
}